// Round 1
// baseline (2819.281 us; speedup 1.0000x reference)
//
#include <hip/hip_runtime.h>
#include <cstddef>
#include <cstdint>

#define BATCH 32
#define SEQ 2048
#define DM 1024

// ---------------- init: zero the atomically-accumulated buffers ----------------
__global__ __launch_bounds__(256) void init_kernel(float* __restrict__ scores,
                                                   float* __restrict__ context) {
    int idx = blockIdx.x * 256 + threadIdx.x;
    if (idx < BATCH * SEQ) scores[idx] = 0.f;
    if (idx < BATCH * DM) context[idx] = 0.f;
}

// ---------------- q projection: q = query @ Wq_w.T + Wq_b ----------------
__global__ __launch_bounds__(256) void qproj_kernel(const float* __restrict__ query,
                                                    const float* __restrict__ Wq_w,
                                                    const float* __restrict__ Wq_b,
                                                    float* __restrict__ q_out) {
    int b = blockIdx.x;
    int tid = threadIdx.x;
    __shared__ float qs[DM];
    for (int i = tid; i < DM; i += 256) qs[i] = query[b * DM + i];
    __syncthreads();
    for (int d = tid; d < DM; d += 256) {
        const float4* w4 = reinterpret_cast<const float4*>(Wq_w + (size_t)d * DM);
        float acc = Wq_b[d];
#pragma unroll 4
        for (int e4 = 0; e4 < DM / 4; ++e4) {
            float4 w = w4[e4];
            acc += w.x * qs[e4 * 4 + 0] + w.y * qs[e4 * 4 + 1] +
                   w.z * qs[e4 * 4 + 2] + w.w * qs[e4 * 4 + 3];
        }
        q_out[b * DM + d] = acc;
    }
}

// ---------------- scores: fused k-projection + tanh + v_w dot ----------------
// scores[m] += sum_{d in n-chunk} tanh( (keys[m,:] . Wk_w[d,:]) + Wk_b[d] + q[b,d] ) * v_w[d]
#define BM 64
#define BN 64
#define BK 16

__global__ __launch_bounds__(256) void scores_kernel(const float* __restrict__ keys,
                                                     const float* __restrict__ Wk_w,
                                                     const float* __restrict__ Wk_b,
                                                     const float* __restrict__ q,
                                                     const float* __restrict__ v_w,
                                                     float* __restrict__ scores) {
    int mtile = blockIdx.x >> 4;   // 1024 m-tiles
    int nchunk = blockIdx.x & 15;  // 16 n-chunks (fast-varying: A-tile L2 reuse)
    int m0 = mtile * BM;
    int n0 = nchunk * BN;
    int b = m0 >> 11;              // m0 / SEQ; BM=64 divides SEQ=2048 -> one b per tile
    int tid = threadIdx.x;
    int tx = tid & 15, ty = tid >> 4;

    __shared__ float As[BM][BK + 1];   // pad 17: conflict-free strided reads
    __shared__ float Bs[BN][BK + 1];

    float acc[4][4] = {};

    int lrow = tid >> 2;          // 0..63
    int lk = (tid & 3) * 4;       // 0,4,8,12

    const float* Ag = keys + (size_t)(m0 + lrow) * DM + lk;
    const float* Bg = Wk_w + (size_t)(n0 + lrow) * DM + lk;

    for (int k0 = 0; k0 < DM; k0 += BK) {
        float4 av = *reinterpret_cast<const float4*>(Ag + k0);
        float4 bv = *reinterpret_cast<const float4*>(Bg + k0);
        As[lrow][lk + 0] = av.x; As[lrow][lk + 1] = av.y;
        As[lrow][lk + 2] = av.z; As[lrow][lk + 3] = av.w;
        Bs[lrow][lk + 0] = bv.x; Bs[lrow][lk + 1] = bv.y;
        Bs[lrow][lk + 2] = bv.z; Bs[lrow][lk + 3] = bv.w;
        __syncthreads();
#pragma unroll
        for (int k = 0; k < BK; ++k) {
            float a[4], bb[4];
#pragma unroll
            for (int i = 0; i < 4; ++i) a[i] = As[ty * 4 + i][k];
#pragma unroll
            for (int j = 0; j < 4; ++j) bb[j] = Bs[tx * 4 + j][k];
#pragma unroll
            for (int i = 0; i < 4; ++i)
#pragma unroll
                for (int j = 0; j < 4; ++j)
                    acc[i][j] += a[i] * bb[j];
        }
        __syncthreads();
    }

    // epilogue: tanh, * v_w, reduce over this block's 64 dims
    float rowp[4];
#pragma unroll
    for (int i = 0; i < 4; ++i) {
        float p = 0.f;
#pragma unroll
        for (int j = 0; j < 4; ++j) {
            int d = n0 + tx * 4 + j;
            float val = acc[i][j] + q[b * DM + d] + Wk_b[d];
            p += tanhf(val) * v_w[d];
        }
        rowp[i] = p;
    }
    // reduce across the 16 tx lanes (same ty => same 16-lane group within a wave)
#pragma unroll
    for (int off = 8; off >= 1; off >>= 1) {
#pragma unroll
        for (int i = 0; i < 4; ++i)
            rowp[i] += __shfl_xor(rowp[i], off, 16);
    }
    if (tx == 0) {
#pragma unroll
        for (int i = 0; i < 4; ++i)
            atomicAdd(&scores[m0 + ty * 4 + i], rowp[i]);
    }
}

// ---------------- softmax over S per batch row ----------------
__global__ __launch_bounds__(256) void softmax_kernel(const float* __restrict__ scores,
                                                      float* __restrict__ attn) {
    int b = blockIdx.x;
    int tid = threadIdx.x;
    __shared__ float redm[4];
    __shared__ float reds[4];
    float v[8];
    float mx = -1e30f;
#pragma unroll
    for (int i = 0; i < 8; ++i) {
        v[i] = scores[b * SEQ + i * 256 + tid];
        mx = fmaxf(mx, v[i]);
    }
#pragma unroll
    for (int off = 32; off >= 1; off >>= 1) mx = fmaxf(mx, __shfl_xor(mx, off));
    int wid = tid >> 6;
    if ((tid & 63) == 0) redm[wid] = mx;
    __syncthreads();
    mx = fmaxf(fmaxf(redm[0], redm[1]), fmaxf(redm[2], redm[3]));
    float sum = 0.f;
#pragma unroll
    for (int i = 0; i < 8; ++i) {
        v[i] = expf(v[i] - mx);
        sum += v[i];
    }
#pragma unroll
    for (int off = 32; off >= 1; off >>= 1) sum += __shfl_xor(sum, off);
    if ((tid & 63) == 0) reds[wid] = sum;
    __syncthreads();
    sum = reds[0] + reds[1] + reds[2] + reds[3];
    float inv = 1.f / sum;
#pragma unroll
    for (int i = 0; i < 8; ++i) attn[b * SEQ + i * 256 + tid] = v[i] * inv;
}

// ---------------- context = attn @ keys ----------------
__global__ __launch_bounds__(256) void context_kernel(const float* __restrict__ keys,
                                                      const float* __restrict__ attn,
                                                      float* __restrict__ context) {
    int id = blockIdx.x;           // 32 b * 4 dchunk * 8 schunk = 1024 blocks
    int schunk = id & 7;
    int dchunk = (id >> 3) & 3;
    int b = id >> 5;
    int tid = threadIdx.x;
    int d = dchunk * 256 + tid;
    __shared__ float a_s[256];
    a_s[tid] = attn[b * SEQ + schunk * 256 + tid];
    __syncthreads();
    const float* kp = keys + ((size_t)b * SEQ + (size_t)schunk * 256) * DM + d;
    float acc = 0.f;
#pragma unroll 8
    for (int s = 0; s < 256; ++s) acc += a_s[s] * kp[(size_t)s * DM];
    atomicAdd(&context[b * DM + d], acc);
}

extern "C" void kernel_launch(void* const* d_in, const int* in_sizes, int n_in,
                              void* d_out, int out_size, void* d_ws, size_t ws_size,
                              hipStream_t stream) {
    const float* query = (const float*)d_in[0];
    const float* keys  = (const float*)d_in[1];
    const float* Wq_w  = (const float*)d_in[2];
    const float* Wq_b  = (const float*)d_in[3];
    const float* Wk_w  = (const float*)d_in[4];
    const float* Wk_b  = (const float*)d_in[5];
    const float* v_w   = (const float*)d_in[6];
    // d_in[7] = v_b: additive constant on all scores -> cancels exactly in softmax.

    float* context = (float*)d_out;              // [32][1024]
    float* attn    = context + BATCH * DM;       // [32][2048]

    float* q      = (float*)d_ws;                // [32][1024]
    float* scores = q + BATCH * DM;              // [32][2048]

    hipLaunchKernelGGL(init_kernel, dim3(256), dim3(256), 0, stream, scores, context);
    hipLaunchKernelGGL(qproj_kernel, dim3(BATCH), dim3(256), 0, stream,
                       query, Wq_w, Wq_b, q);
    hipLaunchKernelGGL(scores_kernel, dim3((BATCH * SEQ / BM) * (DM / BN)), dim3(256), 0, stream,
                       keys, Wk_w, Wk_b, q, v_w, scores);
    hipLaunchKernelGGL(softmax_kernel, dim3(BATCH), dim3(256), 0, stream, scores, attn);
    hipLaunchKernelGGL(context_kernel, dim3(1024), dim3(256), 0, stream, keys, attn, context);
}

// Round 2
// 598.352 us; speedup vs baseline: 4.7117x; 4.7117x over previous
//
#include <hip/hip_runtime.h>
#include <cstddef>
#include <cstdint>

#define BATCH 32
#define SEQ 2048
#define DM 1024

typedef __attribute__((ext_vector_type(8))) short short8v;
typedef __attribute__((ext_vector_type(4))) float f32x4;

// split fp32 into hi (truncated bf16) + lo (bf16 of residual); error ~2^-16 rel
__device__ __forceinline__ void bsplit(float f, unsigned short& h, unsigned short& l) {
    unsigned u = __float_as_uint(f);
    h = (unsigned short)(u >> 16);
    float hf = __uint_as_float(u & 0xFFFF0000u);
    unsigned ul = __float_as_uint(f - hf);
    l = (unsigned short)(ul >> 16);
}

// tanh(x) = 1 - 2/(e^{2x}+1); saturates to +-1 correctly for |x| large
__device__ __forceinline__ float tanh_fast(float x) {
    float e = __expf(2.0f * x);
    return 1.0f - 2.0f / (e + 1.0f);
}

// ---------------- init: zero the atomically-accumulated buffers ----------------
__global__ __launch_bounds__(256) void init_kernel(float* __restrict__ scores,
                                                   float* __restrict__ context) {
    int idx = blockIdx.x * 256 + threadIdx.x;
    if (idx < BATCH * SEQ) scores[idx] = 0.f;
    if (idx < BATCH * DM) context[idx] = 0.f;
}

// ---------------- q projection: q = query @ Wq_w.T + Wq_b ----------------
__global__ __launch_bounds__(256) void qproj_kernel(const float* __restrict__ query,
                                                    const float* __restrict__ Wq_w,
                                                    const float* __restrict__ Wq_b,
                                                    float* __restrict__ q_out) {
    int b = blockIdx.x;
    int tid = threadIdx.x;
    __shared__ float qs[DM];
    for (int i = tid; i < DM; i += 256) qs[i] = query[b * DM + i];
    __syncthreads();
    for (int d = tid; d < DM; d += 256) {
        const float4* w4 = reinterpret_cast<const float4*>(Wq_w + (size_t)d * DM);
        float acc = Wq_b[d];
#pragma unroll 4
        for (int e4 = 0; e4 < DM / 4; ++e4) {
            float4 w = w4[e4];
            acc += w.x * qs[e4 * 4 + 0] + w.y * qs[e4 * 4 + 1] +
                   w.z * qs[e4 * 4 + 2] + w.w * qs[e4 * 4 + 3];
        }
        q_out[b * DM + d] = acc;
    }
}

// ---------------- scores: split-bf16 MFMA GEMM + fused tanh/v_w epilogue ----------------
// C[m][n] = keys[m,:] . Wk_w[n,:]  (B^T layout: both operands [rows][K] row-major)
// scores[m] += sum_n tanh(C + q[b,n] + Wk_b[n]) * v_w[n]
#define BM 128
#define BN 128
#define BK 32
#define LDK 40   // pad 32->40 shorts (80B rows, 16B aligned): uniform bank-quad usage

__global__ __launch_bounds__(256, 2) void scores_kernel(const float* __restrict__ keys,
                                                        const float* __restrict__ Wk_w,
                                                        const float* __restrict__ Wk_b,
                                                        const float* __restrict__ q,
                                                        const float* __restrict__ v_w,
                                                        float* __restrict__ scores) {
    __shared__ unsigned short Ah[BM][LDK];
    __shared__ unsigned short Al[BM][LDK];
    __shared__ unsigned short Bh[BM][LDK];
    __shared__ unsigned short Bl[BM][LDK];

    const int mtile = blockIdx.x >> 3;   // 512 m-tiles
    const int nchunk = blockIdx.x & 7;   // 8 n-chunks fast: A-tile L2/L3 reuse
    const int m0 = mtile * BM;
    const int n0 = nchunk * BN;
    const int b = m0 >> 11;              // BM=128 divides SEQ=2048

    const int t = threadIdx.x;
    const int w = t >> 6, l = t & 63;
    const int wm = w >> 1, wn = w & 1;   // 2x2 wave grid, 64x64 per wave
    const int lr = l & 15, lg = l >> 4;

    const int r = t >> 1;                // staging row 0..127
    const int h = t & 1;                 // staging K-half (16 elems)

    const float* Ap = keys + (size_t)(m0 + r) * DM + h * 16;
    const float* Bp = Wk_w + (size_t)(n0 + r) * DM + h * 16;

    float4 bufA[4], bufB[4];
#pragma unroll
    for (int j = 0; j < 4; ++j) {
        bufA[j] = *reinterpret_cast<const float4*>(Ap + 4 * j);
        bufB[j] = *reinterpret_cast<const float4*>(Bp + 4 * j);
    }

    f32x4 acc[4][4];
#pragma unroll
    for (int mi = 0; mi < 4; ++mi)
#pragma unroll
        for (int ni = 0; ni < 4; ++ni)
#pragma unroll
            for (int c = 0; c < 4; ++c) acc[mi][ni][c] = 0.f;

    union U8 { unsigned short u[8]; short8v v; };

    for (int k0 = 0; k0 < DM; k0 += BK) {
        U8 ha0, ha1, la0, la1, hb0, hb1, lb0, lb1;
#pragma unroll
        for (int j = 0; j < 4; ++j) {
            const float* fa = reinterpret_cast<const float*>(&bufA[j]);
            const float* fb = reinterpret_cast<const float*>(&bufB[j]);
#pragma unroll
            for (int c = 0; c < 4; ++c) {
                int idx = j * 4 + c;
                if (idx < 8) {
                    bsplit(fa[c], ha0.u[idx], la0.u[idx]);
                    bsplit(fb[c], hb0.u[idx], lb0.u[idx]);
                } else {
                    bsplit(fa[c], ha1.u[idx - 8], la1.u[idx - 8]);
                    bsplit(fb[c], hb1.u[idx - 8], lb1.u[idx - 8]);
                }
            }
        }
        __syncthreads();   // previous iter's frag reads done
        *reinterpret_cast<short8v*>(&Ah[r][h * 16])     = ha0.v;
        *reinterpret_cast<short8v*>(&Ah[r][h * 16 + 8]) = ha1.v;
        *reinterpret_cast<short8v*>(&Al[r][h * 16])     = la0.v;
        *reinterpret_cast<short8v*>(&Al[r][h * 16 + 8]) = la1.v;
        *reinterpret_cast<short8v*>(&Bh[r][h * 16])     = hb0.v;
        *reinterpret_cast<short8v*>(&Bh[r][h * 16 + 8]) = hb1.v;
        *reinterpret_cast<short8v*>(&Bl[r][h * 16])     = lb0.v;
        *reinterpret_cast<short8v*>(&Bl[r][h * 16 + 8]) = lb1.v;
        __syncthreads();

        if (k0 + BK < DM) {   // prefetch next fp32 tiles; overlaps MFMA below
#pragma unroll
            for (int j = 0; j < 4; ++j) {
                bufA[j] = *reinterpret_cast<const float4*>(Ap + (k0 + BK) + 4 * j);
                bufB[j] = *reinterpret_cast<const float4*>(Bp + (k0 + BK) + 4 * j);
            }
        }

        short8v bhf[4], blf[4];
#pragma unroll
        for (int ni = 0; ni < 4; ++ni) {
            int row = wn * 64 + ni * 16 + lr;
            bhf[ni] = *reinterpret_cast<const short8v*>(&Bh[row][lg * 8]);
            blf[ni] = *reinterpret_cast<const short8v*>(&Bl[row][lg * 8]);
        }
#pragma unroll
        for (int mi = 0; mi < 4; ++mi) {
            int row = wm * 64 + mi * 16 + lr;
            short8v ahf = *reinterpret_cast<const short8v*>(&Ah[row][lg * 8]);
            short8v alf = *reinterpret_cast<const short8v*>(&Al[row][lg * 8]);
#pragma unroll
            for (int ni = 0; ni < 4; ++ni) {
                acc[mi][ni] = __builtin_amdgcn_mfma_f32_16x16x32_bf16(ahf, bhf[ni], acc[mi][ni], 0, 0, 0);
                acc[mi][ni] = __builtin_amdgcn_mfma_f32_16x16x32_bf16(alf, bhf[ni], acc[mi][ni], 0, 0, 0);
                acc[mi][ni] = __builtin_amdgcn_mfma_f32_16x16x32_bf16(ahf, blf[ni], acc[mi][ni], 0, 0, 0);
            }
        }
    }

    // epilogue: tanh * v_w, reduce over this block's 128 n-dims, atomic per row
    float qb[4], vw[4];
#pragma unroll
    for (int ni = 0; ni < 4; ++ni) {
        int n = n0 + wn * 64 + ni * 16 + lr;
        qb[ni] = q[b * DM + n] + Wk_b[n];
        vw[ni] = v_w[n];
    }
#pragma unroll
    for (int mi = 0; mi < 4; ++mi) {
#pragma unroll
        for (int rg = 0; rg < 4; ++rg) {
            float p = 0.f;
#pragma unroll
            for (int ni = 0; ni < 4; ++ni) {
                float val = acc[mi][ni][rg] + qb[ni];
                p += tanh_fast(val) * vw[ni];
            }
#pragma unroll
            for (int off = 8; off >= 1; off >>= 1) p += __shfl_xor(p, off, 16);
            if (lr == 0)
                atomicAdd(&scores[m0 + wm * 64 + mi * 16 + lg * 4 + rg], p);
        }
    }
}

// ---------------- softmax over S per batch row ----------------
__global__ __launch_bounds__(256) void softmax_kernel(const float* __restrict__ scores,
                                                      float* __restrict__ attn) {
    int b = blockIdx.x;
    int tid = threadIdx.x;
    __shared__ float redm[4];
    __shared__ float reds[4];
    float v[8];
    float mx = -1e30f;
#pragma unroll
    for (int i = 0; i < 8; ++i) {
        v[i] = scores[b * SEQ + i * 256 + tid];
        mx = fmaxf(mx, v[i]);
    }
#pragma unroll
    for (int off = 32; off >= 1; off >>= 1) mx = fmaxf(mx, __shfl_xor(mx, off));
    int wid = tid >> 6;
    if ((tid & 63) == 0) redm[wid] = mx;
    __syncthreads();
    mx = fmaxf(fmaxf(redm[0], redm[1]), fmaxf(redm[2], redm[3]));
    float sum = 0.f;
#pragma unroll
    for (int i = 0; i < 8; ++i) {
        v[i] = expf(v[i] - mx);
        sum += v[i];
    }
#pragma unroll
    for (int off = 32; off >= 1; off >>= 1) sum += __shfl_xor(sum, off);
    if ((tid & 63) == 0) reds[wid] = sum;
    __syncthreads();
    sum = reds[0] + reds[1] + reds[2] + reds[3];
    float inv = 1.f / sum;
#pragma unroll
    for (int i = 0; i < 8; ++i) attn[b * SEQ + i * 256 + tid] = v[i] * inv;
}

// ---------------- context = attn @ keys ----------------
__global__ __launch_bounds__(256) void context_kernel(const float* __restrict__ keys,
                                                      const float* __restrict__ attn,
                                                      float* __restrict__ context) {
    int id = blockIdx.x;           // 32 b * 4 dchunk * 8 schunk = 1024 blocks
    int schunk = id & 7;
    int dchunk = (id >> 3) & 3;
    int b = id >> 5;
    int tid = threadIdx.x;
    int d = dchunk * 256 + tid;
    __shared__ float a_s[256];
    a_s[tid] = attn[b * SEQ + schunk * 256 + tid];
    __syncthreads();
    const float* kp = keys + ((size_t)b * SEQ + (size_t)schunk * 256) * DM + d;
    float acc = 0.f;
#pragma unroll 8
    for (int s = 0; s < 256; ++s) acc += a_s[s] * kp[(size_t)s * DM];
    atomicAdd(&context[b * DM + d], acc);
}

extern "C" void kernel_launch(void* const* d_in, const int* in_sizes, int n_in,
                              void* d_out, int out_size, void* d_ws, size_t ws_size,
                              hipStream_t stream) {
    const float* query = (const float*)d_in[0];
    const float* keys  = (const float*)d_in[1];
    const float* Wq_w  = (const float*)d_in[2];
    const float* Wq_b  = (const float*)d_in[3];
    const float* Wk_w  = (const float*)d_in[4];
    const float* Wk_b  = (const float*)d_in[5];
    const float* v_w   = (const float*)d_in[6];
    // d_in[7] = v_b: additive constant on all scores -> cancels exactly in softmax.

    float* context = (float*)d_out;              // [32][1024]
    float* attn    = context + BATCH * DM;       // [32][2048]

    float* q      = (float*)d_ws;                // [32][1024]
    float* scores = q + BATCH * DM;              // [32][2048]

    hipLaunchKernelGGL(init_kernel, dim3(256), dim3(256), 0, stream, scores, context);
    hipLaunchKernelGGL(qproj_kernel, dim3(BATCH), dim3(256), 0, stream,
                       query, Wq_w, Wq_b, q);
    hipLaunchKernelGGL(scores_kernel, dim3((BATCH * SEQ / BM) * (DM / BN)), dim3(256), 0, stream,
                       keys, Wk_w, Wk_b, q, v_w, scores);
    hipLaunchKernelGGL(softmax_kernel, dim3(BATCH), dim3(256), 0, stream, scores, attn);
    hipLaunchKernelGGL(context_kernel, dim3(1024), dim3(256), 0, stream, keys, attn, context);
}

// Round 3
// 539.423 us; speedup vs baseline: 5.2265x; 1.1092x over previous
//
#include <hip/hip_runtime.h>
#include <cstddef>
#include <cstdint>

#define BATCH 32
#define SEQ 2048
#define DM 1024

typedef __attribute__((ext_vector_type(8))) _Float16 half8v;
typedef __attribute__((ext_vector_type(4))) float f32x4;

// tanh(x) = 1 - 2/(e^{2x}+1); saturates to +-1 correctly for |x| large
__device__ __forceinline__ float tanh_fast(float x) {
    float e = __expf(2.0f * x);
    return 1.0f - 2.0f / (e + 1.0f);
}

// ---------------- init: zero the atomically-accumulated buffers ----------------
__global__ __launch_bounds__(256) void init_kernel(float* __restrict__ scores,
                                                   float* __restrict__ context) {
    int idx = blockIdx.x * 256 + threadIdx.x;
    if (idx < BATCH * SEQ) scores[idx] = 0.f;
    if (idx < BATCH * DM) context[idx] = 0.f;
}

// ---------------- q projection: q = query @ Wq_w.T + Wq_b ----------------
__global__ __launch_bounds__(256) void qproj_kernel(const float* __restrict__ query,
                                                    const float* __restrict__ Wq_w,
                                                    const float* __restrict__ Wq_b,
                                                    float* __restrict__ q_out) {
    int b = blockIdx.x;
    int tid = threadIdx.x;
    __shared__ float qs[DM];
    for (int i = tid; i < DM; i += 256) qs[i] = query[b * DM + i];
    __syncthreads();
    for (int d = tid; d < DM; d += 256) {
        const float4* w4 = reinterpret_cast<const float4*>(Wq_w + (size_t)d * DM);
        float acc = Wq_b[d];
#pragma unroll 4
        for (int e4 = 0; e4 < DM / 4; ++e4) {
            float4 w = w4[e4];
            acc += w.x * qs[e4 * 4 + 0] + w.y * qs[e4 * 4 + 1] +
                   w.z * qs[e4 * 4 + 2] + w.w * qs[e4 * 4 + 3];
        }
        q_out[b * DM + d] = acc;
    }
}

// ---------------- scores: fp16 2-term split MFMA GEMM + fused tanh/v_w epilogue -------
// C[m][n] = keys[m,:] . Wk_w[n,:]  ~= (Ah+Al)@Bh  (fp16 hi/lo split of A, fp16 B)
// scores[m] += sum_n tanh(C + q[b,n] + Wk_b[n]) * v_w[n]
#define BM 128
#define BN 128
#define BK 32

__global__ __launch_bounds__(256, 2) void scores_kernel(const float* __restrict__ keys,
                                                        const float* __restrict__ Wk_w,
                                                        const float* __restrict__ Wk_b,
                                                        const float* __restrict__ q,
                                                        const float* __restrict__ v_w,
                                                        float* __restrict__ scores) {
    // K-subtiled LDS: [k-chunk][row][8 halfs]. Row stride 16 B -> ds_read_b128 /
    // ds_write_b128 touch each bank-quad exactly 8 lanes/wave (minimal, conflict-free).
    __shared__ _Float16 Ah[BK / 8][BM][8];
    __shared__ _Float16 Al[BK / 8][BM][8];
    __shared__ _Float16 Bh[BK / 8][BM][8];

    // XCD swizzle: 4096 blocks = 8 XCDs x 512. Same-XCD blocks get a contiguous
    // logical range; nchunk-major inside so one 512KB B-tile stays L2-resident
    // while the XCD's keys rows stream through (keys fetched from HBM once).
    const unsigned bid = blockIdx.x;
    const unsigned swz = (bid & 7u) * 512u + (bid >> 3);
    const int xg = swz >> 9;               // 0..7  (per-XCD m-range group)
    const int kk = swz & 511;
    const int nchunk = kk >> 6;            // 0..7  (slow inside XCD)
    const int mtile = xg * 64 + (kk & 63); // 0..511
    const int m0 = mtile * BM;
    const int n0 = nchunk * BN;
    const int b = m0 >> 11;                // BM=128 divides SEQ=2048

    const int t = threadIdx.x;
    const int w = t >> 6, l = t & 63;
    const int wm = w >> 1, wn = w & 1;     // 2x2 wave grid, 64x64 per wave
    const int lr = l & 15, lg = l >> 4;

    const int r = t >> 1;                  // staging row 0..127
    const int h = t & 1;                   // staging K-half (16 elems)

    const float* Ap = keys + (size_t)(m0 + r) * DM + h * 16;
    const float* Bp = Wk_w + (size_t)(n0 + r) * DM + h * 16;

    float4 bufA[4], bufB[4];
#pragma unroll
    for (int j = 0; j < 4; ++j) {
        bufA[j] = *reinterpret_cast<const float4*>(Ap + 4 * j);
        bufB[j] = *reinterpret_cast<const float4*>(Bp + 4 * j);
    }

    f32x4 acc[4][4];
#pragma unroll
    for (int mi = 0; mi < 4; ++mi)
#pragma unroll
        for (int ni = 0; ni < 4; ++ni)
#pragma unroll
            for (int c = 0; c < 4; ++c) acc[mi][ni][c] = 0.f;

    union H8 { _Float16 f[8]; half8v v; };

    for (int k0 = 0; k0 < DM; k0 += BK) {
        H8 ah0, ah1, al0, al1, bh0, bh1;
#pragma unroll
        for (int j = 0; j < 4; ++j) {
            const float* fa = reinterpret_cast<const float*>(&bufA[j]);
            const float* fb = reinterpret_cast<const float*>(&bufB[j]);
#pragma unroll
            for (int c = 0; c < 4; ++c) {
                int idx = j * 4 + c;
                _Float16 hi = (_Float16)fa[c];
                _Float16 lo = (_Float16)(fa[c] - (float)hi);
                _Float16 bb = (_Float16)fb[c];
                if (idx < 8) { ah0.f[idx] = hi; al0.f[idx] = lo; bh0.f[idx] = bb; }
                else         { ah1.f[idx - 8] = hi; al1.f[idx - 8] = lo; bh1.f[idx - 8] = bb; }
            }
        }
        __syncthreads();   // previous iter's frag reads done
        *reinterpret_cast<half8v*>(&Ah[2 * h][r][0])     = ah0.v;
        *reinterpret_cast<half8v*>(&Ah[2 * h + 1][r][0]) = ah1.v;
        *reinterpret_cast<half8v*>(&Al[2 * h][r][0])     = al0.v;
        *reinterpret_cast<half8v*>(&Al[2 * h + 1][r][0]) = al1.v;
        *reinterpret_cast<half8v*>(&Bh[2 * h][r][0])     = bh0.v;
        *reinterpret_cast<half8v*>(&Bh[2 * h + 1][r][0]) = bh1.v;
        __syncthreads();

        if (k0 + BK < DM) {   // prefetch next fp32 tiles; overlaps MFMA below
#pragma unroll
            for (int j = 0; j < 4; ++j) {
                bufA[j] = *reinterpret_cast<const float4*>(Ap + (k0 + BK) + 4 * j);
                bufB[j] = *reinterpret_cast<const float4*>(Bp + (k0 + BK) + 4 * j);
            }
        }

        half8v bhv[4];
#pragma unroll
        for (int ni = 0; ni < 4; ++ni)
            bhv[ni] = *reinterpret_cast<const half8v*>(&Bh[lg][wn * 64 + ni * 16 + lr][0]);
#pragma unroll
        for (int mi = 0; mi < 4; ++mi) {
            int row = wm * 64 + mi * 16 + lr;
            half8v ahv = *reinterpret_cast<const half8v*>(&Ah[lg][row][0]);
            half8v alv = *reinterpret_cast<const half8v*>(&Al[lg][row][0]);
#pragma unroll
            for (int ni = 0; ni < 4; ++ni) {
                acc[mi][ni] = __builtin_amdgcn_mfma_f32_16x16x32_f16(ahv, bhv[ni], acc[mi][ni], 0, 0, 0);
                acc[mi][ni] = __builtin_amdgcn_mfma_f32_16x16x32_f16(alv, bhv[ni], acc[mi][ni], 0, 0, 0);
            }
        }
    }

    // epilogue: tanh * v_w, reduce over this block's 128 n-dims, atomic per row
    float qb[4], vw[4];
#pragma unroll
    for (int ni = 0; ni < 4; ++ni) {
        int n = n0 + wn * 64 + ni * 16 + lr;
        qb[ni] = q[b * DM + n] + Wk_b[n];
        vw[ni] = v_w[n];
    }
#pragma unroll
    for (int mi = 0; mi < 4; ++mi) {
#pragma unroll
        for (int rg = 0; rg < 4; ++rg) {
            float p = 0.f;
#pragma unroll
            for (int ni = 0; ni < 4; ++ni) {
                float val = acc[mi][ni][rg] + qb[ni];
                p += tanh_fast(val) * vw[ni];
            }
#pragma unroll
            for (int off = 8; off >= 1; off >>= 1) p += __shfl_xor(p, off, 16);
            if (lr == 0)
                atomicAdd(&scores[m0 + wm * 64 + mi * 16 + lg * 4 + rg], p);
        }
    }
}

// ---------------- softmax over S per batch row ----------------
__global__ __launch_bounds__(256) void softmax_kernel(const float* __restrict__ scores,
                                                      float* __restrict__ attn) {
    int b = blockIdx.x;
    int tid = threadIdx.x;
    __shared__ float redm[4];
    __shared__ float reds[4];
    float v[8];
    float mx = -1e30f;
#pragma unroll
    for (int i = 0; i < 8; ++i) {
        v[i] = scores[b * SEQ + i * 256 + tid];
        mx = fmaxf(mx, v[i]);
    }
#pragma unroll
    for (int off = 32; off >= 1; off >>= 1) mx = fmaxf(mx, __shfl_xor(mx, off));
    int wid = tid >> 6;
    if ((tid & 63) == 0) redm[wid] = mx;
    __syncthreads();
    mx = fmaxf(fmaxf(redm[0], redm[1]), fmaxf(redm[2], redm[3]));
    float sum = 0.f;
#pragma unroll
    for (int i = 0; i < 8; ++i) {
        v[i] = expf(v[i] - mx);
        sum += v[i];
    }
#pragma unroll
    for (int off = 32; off >= 1; off >>= 1) sum += __shfl_xor(sum, off);
    if ((tid & 63) == 0) reds[wid] = sum;
    __syncthreads();
    sum = reds[0] + reds[1] + reds[2] + reds[3];
    float inv = 1.f / sum;
#pragma unroll
    for (int i = 0; i < 8; ++i) attn[b * SEQ + i * 256 + tid] = v[i] * inv;
}

// ---------------- context = attn @ keys ----------------
__global__ __launch_bounds__(256) void context_kernel(const float* __restrict__ keys,
                                                      const float* __restrict__ attn,
                                                      float* __restrict__ context) {
    int id = blockIdx.x;           // 32 b * 4 dchunk * 8 schunk = 1024 blocks
    int schunk = id & 7;
    int dchunk = (id >> 3) & 3;
    int b = id >> 5;
    int tid = threadIdx.x;
    int d = dchunk * 256 + tid;
    __shared__ float a_s[256];
    a_s[tid] = attn[b * SEQ + schunk * 256 + tid];
    __syncthreads();
    const float* kp = keys + ((size_t)b * SEQ + (size_t)schunk * 256) * DM + d;
    float acc = 0.f;
#pragma unroll 8
    for (int s = 0; s < 256; ++s) acc += a_s[s] * kp[(size_t)s * DM];
    atomicAdd(&context[b * DM + d], acc);
}

extern "C" void kernel_launch(void* const* d_in, const int* in_sizes, int n_in,
                              void* d_out, int out_size, void* d_ws, size_t ws_size,
                              hipStream_t stream) {
    const float* query = (const float*)d_in[0];
    const float* keys  = (const float*)d_in[1];
    const float* Wq_w  = (const float*)d_in[2];
    const float* Wq_b  = (const float*)d_in[3];
    const float* Wk_w  = (const float*)d_in[4];
    const float* Wk_b  = (const float*)d_in[5];
    const float* v_w   = (const float*)d_in[6];
    // d_in[7] = v_b: additive constant on all scores -> cancels exactly in softmax.

    float* context = (float*)d_out;              // [32][1024]
    float* attn    = context + BATCH * DM;       // [32][2048]

    float* q      = (float*)d_ws;                // [32][1024]
    float* scores = q + BATCH * DM;              // [32][2048]

    hipLaunchKernelGGL(init_kernel, dim3(256), dim3(256), 0, stream, scores, context);
    hipLaunchKernelGGL(qproj_kernel, dim3(BATCH), dim3(256), 0, stream,
                       query, Wq_w, Wq_b, q);
    hipLaunchKernelGGL(scores_kernel, dim3((BATCH * SEQ / BM) * (DM / BN)), dim3(256), 0, stream,
                       keys, Wk_w, Wk_b, q, v_w, scores);
    hipLaunchKernelGGL(softmax_kernel, dim3(BATCH), dim3(256), 0, stream, scores, attn);
    hipLaunchKernelGGL(context_kernel, dim3(1024), dim3(256), 0, stream, keys, attn, context);
}